// Round 7
// baseline (561.853 us; speedup 1.0000x reference)
//
#include <hip/hip_runtime.h>

// MaskedNormalize: x (16, 4, 1024, 1024) fp32. valid = x != 0.
// out = valid ? (x - mean) / (sqrt(var) + eps) : 0, per-sample masked stats.
// Masked-out entries are exactly 0 -> contribute nothing to S1/S2; m2 == 0 analytically.
//
// Round-7: fused single kernel, per-sample flag sync, REGULAR launch.
// Round-6 failed with absmax 5.4375 == max|ref| -> output all zeros -> the
// 2048-block coop launch was rejected (exactly at the 2048-thread/CU cap) and the
// error was unchecked. Fix: round-1's PROVEN-resident geometry (1024 blocks, 4/CU)
// and a regular launch -- co-residency guaranteed by capacity arithmetic:
// __launch_bounds__(256,4) => VGPR<=128 => >=4 blocks/CU * 256 CU = 1024 slots >=
// grid, 2x margin at actual VGPR. No coop API = no launch-size rejection.
//
// Why fuse at all: round-1's fused kernel moved only 537 MB HBM (not 805) -- the
// MALL retained all 256 MiB of x within one dispatch; every cross-dispatch variant
// (r2-r5) pays the full 268 MB re-read regardless of order/hints/chunking.
// Round-1's slowness was the sync, not the traffic: grid.sync() acquire-polls spam
// cache invalidates over co-resident streaming blocks. Here:
//   - per-sample flags: sample s's 64 blocks wait only on each other; phases
//     pipeline across samples, no global tail.
//   - spin = RELAXED agent-scope polls (coherence-point read, NO invalidate side
//     effects) + s_sleep backoff; one acquire fence after the flag flips.
//   - arrive = acq_rel fetch_add; last arriver wave-reduces 64 triples, publishes
//     {mean, inv}, release-stores the flag.
//   - phase 2 stages 8 float4/iter for ILP; nt stores (out never re-read, must not
//     evict x from the MALL).

#define EPS 1e-5

typedef float v4f __attribute__((ext_vector_type(4)));   // native vec for nt store

constexpr int B              = 16;
constexpr int VEC_PER_SAMPLE = 1 << 20;                  // float4 per sample
constexpr int BLOCKS_PS      = 64;
constexpr int THREADS        = 256;
constexpr int TOTAL_BLOCKS   = B * BLOCKS_PS;            // 1024 = 256 CU * 4
constexpr int VPT            = VEC_PER_SAMPLE / (BLOCKS_PS * THREADS);  // 64 float4

// ws layout
constexpr size_t PART_OFF = 0;                                          // 1024*3 doubles
constexpr size_t FIN_OFF  = (size_t)TOTAL_BLOCKS * 3 * sizeof(double);  // 24576
constexpr size_t CNT_OFF  = FIN_OFF + B * sizeof(float2);               // 24704
constexpr size_t FLAG_OFF = CNT_OFF + B * sizeof(unsigned int);         // 24768

__global__ __launch_bounds__(THREADS, 4)
void fused_masked_norm(const float4* __restrict__ x, v4f* __restrict__ out,
                       double* __restrict__ part, float2* __restrict__ fin,
                       unsigned int* __restrict__ cnt, unsigned int* __restrict__ flag) {
    const int sample = blockIdx.x >> 6;            // / BLOCKS_PS
    const int blk    = blockIdx.x & (BLOCKS_PS - 1);
    const size_t base = (size_t)sample * VEC_PER_SAMPLE
                      + (size_t)blk * (THREADS * VPT);
    const float4* xs = x + base;

    // ---- phase 1: per-block partial {sum, sumsq, count} (proven pass-A body) ----
    // 4 independent fp32 chains, 64 floats/chain (round-1 geometry, absmax-proven).
    float s1[4] = {0.f, 0.f, 0.f, 0.f};
    float s2[4] = {0.f, 0.f, 0.f, 0.f};
    int   cn[4] = {0, 0, 0, 0};

    for (int k = 0; k < VPT; k += 4) {
        #pragma unroll
        for (int u = 0; u < 4; ++u) {
            float4 v = xs[(k + u) * THREADS + threadIdx.x];
            s1[u] += (v.x + v.y) + (v.z + v.w);
            s2[u] += v.x * v.x;
            s2[u] += v.y * v.y;
            s2[u] += v.z * v.z;
            s2[u] += v.w * v.w;
            cn[u] += (v.x != 0.0f) + (v.y != 0.0f) + (v.z != 0.0f) + (v.w != 0.0f);
        }
    }

    double d1 = ((double)s1[0] + s1[1]) + ((double)s1[2] + s1[3]);
    double d2 = ((double)s2[0] + s2[1]) + ((double)s2[2] + s2[3]);
    int    ct = (cn[0] + cn[1]) + (cn[2] + cn[3]);

    #pragma unroll
    for (int off = 32; off > 0; off >>= 1) {
        d1 += __shfl_down(d1, off);
        d2 += __shfl_down(d2, off);
        ct += __shfl_down(ct, off);
    }

    __shared__ double L1[4], L2[4];
    __shared__ int    LC[4];
    __shared__ int    islast;
    __shared__ float2 smi;
    const int wave = threadIdx.x >> 6;
    if ((threadIdx.x & 63) == 0) { L1[wave] = d1; L2[wave] = d2; LC[wave] = ct; }
    __syncthreads();
    if (threadIdx.x == 0) {
        double t1 = (L1[0] + L1[1]) + (L1[2] + L1[3]);
        double t2 = (L2[0] + L2[1]) + (L2[2] + L2[3]);
        int    tc = (LC[0] + LC[1]) + (LC[2] + LC[3]);
        const size_t pb = (size_t)blockIdx.x * 3;
        part[pb + 0] = t1;
        part[pb + 1] = t2;
        part[pb + 2] = (double)tc;
        // acq_rel RMW releases the part stores; the 64th arriver acquires the
        // whole release chain -> sees all 64 triples.
        unsigned int old = __hip_atomic_fetch_add(&cnt[sample], 1u,
                                                  __ATOMIC_ACQ_REL,
                                                  __HIP_MEMORY_SCOPE_AGENT);
        islast = (old == BLOCKS_PS - 1);
    }
    __syncthreads();

    if (islast) {
        // last-arriving block of this sample: wave 0 reduces the 64 triples
        if (threadIdx.x < 64) {
            const double* ps = part + (size_t)sample * BLOCKS_PS * 3;
            double e1 = ps[(size_t)threadIdx.x * 3 + 0];
            double e2 = ps[(size_t)threadIdx.x * 3 + 1];
            double ec = ps[(size_t)threadIdx.x * 3 + 2];
            #pragma unroll
            for (int off = 32; off > 0; off >>= 1) {
                e1 += __shfl_down(e1, off);
                e2 += __shfl_down(e2, off);
                ec += __shfl_down(ec, off);
            }
            if (threadIdx.x == 0) {
                double n    = ec;
                double mean = e1 / n;
                double var  = (e2 - e1 * e1 / n) / (n - 1.0);
                float2 mi;
                mi.x = (float)mean;
                mi.y = (float)(1.0 / (sqrt(var) + EPS));
                fin[sample] = mi;
                smi = mi;
                __hip_atomic_store(&flag[sample], 1u,
                                   __ATOMIC_RELEASE, __HIP_MEMORY_SCOPE_AGENT);
            }
        }
    } else {
        if (threadIdx.x == 0) {
            // relaxed agent-scope polls: read the coherence point, NO cache
            // invalidates while co-resident blocks stream phase 1.
            while (__hip_atomic_load(&flag[sample], __ATOMIC_RELAXED,
                                     __HIP_MEMORY_SCOPE_AGENT) == 0u) {
                __builtin_amdgcn_s_sleep(64);   // ~4k cycles between polls
            }
            __builtin_amdgcn_fence(__ATOMIC_ACQUIRE, "agent");
            smi = fin[sample];
        }
    }
    __syncthreads();
    const float mean = smi.x;
    const float inv  = smi.y;

    // ---- phase 2: normalize own slice; x slice is MALL-resident (same dispatch).
    for (int g = 0; g < VPT; g += 8) {
        float4 v[8];
        #pragma unroll
        for (int u = 0; u < 8; ++u)
            v[u] = xs[(g + u) * THREADS + threadIdx.x];
        #pragma unroll
        for (int u = 0; u < 8; ++u) {
            const size_t idx = base + (size_t)(g + u) * THREADS + threadIdx.x;
            v4f o;
            o.x = (v[u].x != 0.0f) ? (v[u].x - mean) * inv : 0.0f;
            o.y = (v[u].y != 0.0f) ? (v[u].y - mean) * inv : 0.0f;
            o.z = (v[u].z != 0.0f) ? (v[u].z - mean) * inv : 0.0f;
            o.w = (v[u].w != 0.0f) ? (v[u].w - mean) * inv : 0.0f;
            __builtin_nontemporal_store(o, &out[idx]);
        }
    }
}

extern "C" void kernel_launch(void* const* d_in, const int* in_sizes, int n_in,
                              void* d_out, int out_size, void* d_ws, size_t ws_size,
                              hipStream_t stream) {
    const float4*  x    = (const float4*)d_in[0];
    v4f*           out  = (v4f*)d_out;
    double*        part = (double*)((char*)d_ws + PART_OFF);
    float2*        fin  = (float2*)((char*)d_ws + FIN_OFF);
    unsigned int*  cnt  = (unsigned int*)((char*)d_ws + CNT_OFF);
    unsigned int*  flag = (unsigned int*)((char*)d_ws + FLAG_OFF);

    // zero cnt[16] + flag[16] (128 B) each iteration -- graph-capturable memset
    hipMemsetAsync((char*)d_ws + CNT_OFF, 0, 2 * B * sizeof(unsigned int), stream);

    fused_masked_norm<<<TOTAL_BLOCKS, THREADS, 0, stream>>>(x, out, part, fin, cnt, flag);
}